// Round 1
// baseline (1828.001 us; speedup 1.0000x reference)
//
#include <hip/hip_runtime.h>
#include <hip/hip_bf16.h>
#include <math.h>

// Problem constants
#define BATCH 32
#define TLEN  4096
#define DDIM  512
#define TM    32      // rows (b*T+t) per block
#define BLOCK 256     // 4 waves

typedef __attribute__((ext_vector_type(8))) short bf16x8;  // MFMA A/B frag (4 VGPRs)
typedef __attribute__((ext_vector_type(4))) float f32x4;   // MFMA C/D frag
typedef __attribute__((ext_vector_type(4))) short s16x4;   // 8B LDS store

__device__ __forceinline__ short f32_to_bf16_rne(float f) {
    union { float f; unsigned int u; } v; v.f = f;
    unsigned int r = (v.u + 0x7FFFu + ((v.u >> 16) & 1u)) >> 16;
    return (short)r;
}
__device__ __forceinline__ float bf16_to_f32(short s) {
    union { unsigned int u; float f; } v;
    v.u = ((unsigned int)(unsigned short)s) << 16;
    return v.f;
}
// tanh via exp; |x| here <= ~7, clamp for paranoia (e^30 still finite).
__device__ __forceinline__ float fast_tanh(float x) {
    x = fminf(fmaxf(x, -15.f), 15.f);
    float t = __expf(2.0f * x);
    return (t - 1.0f) / (t + 1.0f);
}

// XOR swizzle on 16B (8-short) granules: keeps row stride 512 (64KB total LDS,
// 2 blocks/CU) while making 16 consecutive rows hit distinct bank quads
// (2-way max aliasing = free per m136).
__device__ __forceinline__ int lds_idx(int row, int col) {
    int g = (col >> 3) ^ (row & 7);
    return row * DDIM + (g << 3) + (col & 7);
}

// --- kernel 1: W fp32 -> bf16, zero l/g accumulators -------------------------
__global__ void prep_kernel(const float* __restrict__ W1, const float* __restrict__ W2,
                            short* __restrict__ W1b, short* __restrict__ W2b,
                            float* __restrict__ lbuf, float* __restrict__ gbuf) {
    int i = blockIdx.x * blockDim.x + threadIdx.x;   // 0 .. 262143
    W1b[i] = f32_to_bf16_rne(W1[i]);
    W2b[i] = f32_to_bf16_rne(W2[i]);
    if (i < BATCH * DDIM) { lbuf[i] = 0.f; gbuf[i] = 0.f; }
}

// --- kernel 2: fused u=tanh(hW1^T+b1); s=uW2^T; accumulate l,g ---------------
__global__ __launch_bounds__(BLOCK)
void main_kernel(const float* __restrict__ h,
                 const short* __restrict__ W1b,
                 const float* __restrict__ b1,
                 const short* __restrict__ W2b,
                 float* __restrict__ lbuf, float* __restrict__ gbuf) {
    __shared__ short sh_h[TM * DDIM];   // 32 KB, bf16 h tile (swizzled)
    __shared__ short sh_u[TM * DDIM];   // 32 KB, bf16 u tile (swizzled)

    const int tid  = threadIdx.x;
    const int row0 = blockIdx.x * TM;
    const int b    = row0 / TLEN;

    // ---- stage 1: global fp32 h -> LDS bf16 (coalesced float4 loads) ----
    {
        const float4* hp = (const float4*)(h + (size_t)row0 * DDIM);
        #pragma unroll
        for (int i = 0; i < (TM * DDIM / 4) / BLOCK; ++i) {   // 16 iters
            int idx  = tid + i * BLOCK;          // float4 index
            float4 v = hp[idx];
            int flat = idx * 4;
            int r = flat >> 9;                   // /512
            int c = flat & (DDIM - 1);
            s16x4 p;
            p.x = f32_to_bf16_rne(v.x); p.y = f32_to_bf16_rne(v.y);
            p.z = f32_to_bf16_rne(v.z); p.w = f32_to_bf16_rne(v.w);
            *(s16x4*)&sh_h[lds_idx(r, c)] = p;
        }
    }
    __syncthreads();

    const int wave = tid >> 6;
    const int lane = tid & 63;
    const int quad = lane >> 4;
    const int l16  = lane & 15;
    const int rb   = wave & 1;    // row block: rows rb*16 .. +15
    const int ch   = wave >> 1;   // col half : cols ch*256 .. +255
    const int arow = rb * 16 + l16;
    const int kq   = quad * 8;

    // ---- stage 2: GEMM1  u = tanh(h @ W1^T + b1) ----
    for (int cg = 0; cg < 4; ++cg) {
        f32x4 acc[4] = {};
        const int ncol0 = ch * 256 + cg * 64;
        for (int k0 = 0; k0 < DDIM; k0 += 32) {
            bf16x8 a = *(const bf16x8*)&sh_h[lds_idx(arow, k0 + kq)];
            #pragma unroll
            for (int j = 0; j < 4; ++j) {
                int n = ncol0 + j * 16 + l16;
                bf16x8 bf = *(const bf16x8*)&W1b[(size_t)n * DDIM + k0 + kq];
                acc[j] = __builtin_amdgcn_mfma_f32_16x16x32_bf16(a, bf, acc[j], 0, 0, 0);
            }
        }
        #pragma unroll
        for (int j = 0; j < 4; ++j) {
            int col = ncol0 + j * 16 + l16;
            float bias = b1[col];
            #pragma unroll
            for (int r = 0; r < 4; ++r) {
                int row = rb * 16 + quad * 4 + r;            // C/D: col=lane&15, row=quad*4+reg
                float uval = fast_tanh(acc[j][r] + bias);
                sh_u[lds_idx(row, col)] = f32_to_bf16_rne(uval);
            }
        }
    }
    __syncthreads();

    // ---- stage 3: GEMM2  s = u @ W2^T ; accumulate l = sum_t e^s, g = sum_t h*e^s ----
    for (int cg = 0; cg < 4; ++cg) {
        f32x4 acc[4] = {};
        const int ncol0 = ch * 256 + cg * 64;
        for (int k0 = 0; k0 < DDIM; k0 += 32) {
            bf16x8 a = *(const bf16x8*)&sh_u[lds_idx(arow, k0 + kq)];
            #pragma unroll
            for (int j = 0; j < 4; ++j) {
                int n = ncol0 + j * 16 + l16;
                bf16x8 bf = *(const bf16x8*)&W2b[(size_t)n * DDIM + k0 + kq];
                acc[j] = __builtin_amdgcn_mfma_f32_16x16x32_bf16(a, bf, acc[j], 0, 0, 0);
            }
        }
        #pragma unroll
        for (int j = 0; j < 4; ++j) {
            int col = ncol0 + j * 16 + l16;
            float lsum = 0.f, gsum = 0.f;
            #pragma unroll
            for (int r = 0; r < 4; ++r) {
                int row = rb * 16 + quad * 4 + r;
                float e = __expf(acc[j][r]);                 // no max-sub needed: |s| <= ~18
                float hv = bf16_to_f32(sh_h[lds_idx(row, col)]);
                lsum += e;
                gsum += e * hv;
            }
            // column sums live in 4 quads (lanes l16, l16+16, +32, +48)
            lsum += __shfl_xor(lsum, 16);  lsum += __shfl_xor(lsum, 32);
            gsum += __shfl_xor(gsum, 16);  gsum += __shfl_xor(gsum, 32);
            if (quad == 0) {
                atomicAdd(&lbuf[b * DDIM + col], lsum);
                atomicAdd(&gbuf[b * DDIM + col], gsum);
            }
        }
    }
}

// --- kernel 3: out[d] = sum_b g[b,d] / l[b,d] --------------------------------
__global__ void finish_kernel(const float* __restrict__ lbuf,
                              const float* __restrict__ gbuf,
                              float* __restrict__ out) {
    int d = blockIdx.x * blockDim.x + threadIdx.x;   // 0..511
    float s = 0.f;
    #pragma unroll
    for (int b = 0; b < BATCH; ++b)
        s += gbuf[b * DDIM + d] / lbuf[b * DDIM + d];
    out[d] = s;
}

extern "C" void kernel_launch(void* const* d_in, const int* in_sizes, int n_in,
                              void* d_out, int out_size, void* d_ws, size_t ws_size,
                              hipStream_t stream) {
    const float* h  = (const float*)d_in[0];
    const float* W1 = (const float*)d_in[1];
    const float* b1 = (const float*)d_in[2];
    const float* W2 = (const float*)d_in[3];
    float* out = (float*)d_out;

    char* ws = (char*)d_ws;
    short* W1b = (short*)ws;                         // 512 KB
    short* W2b = (short*)(ws + 512 * 1024);          // 512 KB
    float* lbuf = (float*)(ws + 1024 * 1024);        // 64 KB
    float* gbuf = (float*)(ws + 1024 * 1024 + 64 * 1024); // 64 KB

    prep_kernel<<<(DDIM * DDIM) / 256, 256, 0, stream>>>(W1, W2, W1b, W2b, lbuf, gbuf);
    main_kernel<<<(BATCH * TLEN) / TM, BLOCK, 0, stream>>>(h, W1b, b1, W2b, lbuf, gbuf);
    finish_kernel<<<2, 256, 0, stream>>>(lbuf, gbuf, out);
}

// Round 2
// 641.706 us; speedup vs baseline: 2.8487x; 2.8487x over previous
//
#include <hip/hip_runtime.h>
#include <hip/hip_bf16.h>
#include <math.h>

// Problem constants
#define BATCH 32
#define TLEN  4096
#define DDIM  512
#define BM    64      // rows (b*T+t) per block
#define BLOCK 512     // 8 waves; wave w owns cols [w*64, w*64+64), all BM rows

typedef __attribute__((ext_vector_type(8))) short bf16x8;  // MFMA A/B frag (4 VGPRs)
typedef __attribute__((ext_vector_type(4))) float f32x4;   // MFMA C/D frag
typedef __attribute__((ext_vector_type(4))) short s16x4;   // 8B LDS store

__device__ __forceinline__ short f32_to_bf16_rne(float f) {
    union { float f; unsigned int u; } v; v.f = f;
    unsigned int r = (v.u + 0x7FFFu + ((v.u >> 16) & 1u)) >> 16;
    return (short)r;
}
__device__ __forceinline__ float bf16_to_f32(short s) {
    union { unsigned int u; float f; } v;
    v.u = ((unsigned int)(unsigned short)s) << 16;
    return v.f;
}
__device__ __forceinline__ float fast_tanh(float x) {
    x = fminf(fmaxf(x, -15.f), 15.f);
    float t = __expf(2.0f * x);
    return (t - 1.0f) / (t + 1.0f);
}

// XOR swizzle on 16B (8-short) granules. Row stride stays 512 shorts (1024B,
// bank-aligned), so without swizzle an A-frag read (16 rows, same col granule)
// would be 16-way conflicted. g ^= (row&31) spreads the 16 rows of a frag over
// 16 distinct granules -> uniform bank coverage, ~conflict-free ds_read_b128.
__device__ __forceinline__ int lds_idx(int r, int c) {
    int g = (c >> 3) ^ (r & 31);
    return r * DDIM + (g << 3) + (c & 7);
}

// --- kernel 1: W fp32 -> bf16, zero l/g accumulators -------------------------
__global__ void prep_kernel(const float* __restrict__ W1, const float* __restrict__ W2,
                            short* __restrict__ W1b, short* __restrict__ W2b,
                            float* __restrict__ lbuf, float* __restrict__ gbuf) {
    int i = blockIdx.x * blockDim.x + threadIdx.x;   // 0 .. 262143
    W1b[i] = f32_to_bf16_rne(W1[i]);
    W2b[i] = f32_to_bf16_rne(W2[i]);
    if (i < BATCH * DDIM) { lbuf[i] = 0.f; gbuf[i] = 0.f; }
}

// --- kernel 2: fused u=tanh(hW1^T+b1); s=uW2^T; accumulate l,g ---------------
__global__ __launch_bounds__(BLOCK, 2)
void main_kernel(const float* __restrict__ h,
                 const short* __restrict__ W1b,
                 const float* __restrict__ b1,
                 const short* __restrict__ W2b,
                 float* __restrict__ lbuf, float* __restrict__ gbuf) {
    __shared__ short sh_h[BM * DDIM];   // 64 KB, bf16 h tile (swizzled)
    __shared__ short sh_u[BM * DDIM];   // 64 KB, bf16 u tile (swizzled)

    const int tid  = threadIdx.x;
    const int row0 = blockIdx.x * BM;
    const int b    = row0 / TLEN;       // BM divides TLEN: no batch straddle

    // ---- stage 1: global fp32 h -> LDS bf16 (coalesced float4 loads) ----
    {
        const float4* hp = (const float4*)(h + (size_t)row0 * DDIM);
        #pragma unroll
        for (int i = 0; i < (BM * DDIM / 4) / BLOCK; ++i) {   // 16 iters
            int idx  = tid + i * BLOCK;          // float4 index
            float4 v = hp[idx];
            int flat = idx * 4;
            int r = flat >> 9;                   // /512
            int c = flat & (DDIM - 1);
            s16x4 p;
            p.x = f32_to_bf16_rne(v.x); p.y = f32_to_bf16_rne(v.y);
            p.z = f32_to_bf16_rne(v.z); p.w = f32_to_bf16_rne(v.w);
            *(s16x4*)&sh_h[lds_idx(r, c)] = p;
        }
    }
    __syncthreads();

    const int wave  = tid >> 6;
    const int lane  = tid & 63;
    const int quad  = lane >> 4;
    const int l16   = lane & 15;
    const int wcol0 = wave * 64;        // this wave's 64-col slice
    const int kq    = quad * 8;

    // ================= GEMM1: u = tanh(h @ W1^T + b1) =================
    f32x4 acc[4][4];                    // [rowblk][colblk]
    #pragma unroll
    for (int rb = 0; rb < 4; ++rb)
        #pragma unroll
        for (int cb = 0; cb < 4; ++cb) acc[rb][cb] = (f32x4){0.f, 0.f, 0.f, 0.f};

    {
        // B base: row n = wcol0 + cb*16 + l16, k offset kq. 16B loads.
        const short* Bb = W1b + (size_t)(wcol0 + l16) * DDIM + kq;
        bf16x8 bcur[4], bnxt[4];
        #pragma unroll
        for (int cb = 0; cb < 4; ++cb)
            bcur[cb] = *(const bf16x8*)(Bb + cb * 16 * DDIM);

        for (int k0 = 0; k0 < DDIM; k0 += 32) {
            bf16x8 af[4];
            #pragma unroll
            for (int rb = 0; rb < 4; ++rb)
                af[rb] = *(const bf16x8*)&sh_h[lds_idx(rb * 16 + l16, k0 + kq)];
            // prefetch next k-chunk of B (last iter reads 16B past W1b into
            // adjacent ws buffers -- allocated, unused)
            #pragma unroll
            for (int cb = 0; cb < 4; ++cb)
                bnxt[cb] = *(const bf16x8*)(Bb + cb * 16 * DDIM + k0 + 32);
            #pragma unroll
            for (int cb = 0; cb < 4; ++cb)
                #pragma unroll
                for (int rb = 0; rb < 4; ++rb)
                    acc[rb][cb] = __builtin_amdgcn_mfma_f32_16x16x32_bf16(
                        af[rb], bcur[cb], acc[rb][cb], 0, 0, 0);
            #pragma unroll
            for (int cb = 0; cb < 4; ++cb) bcur[cb] = bnxt[cb];
        }
    }

    // epilogue 1: tanh + bias -> sh_u (bf16, swizzled)
    #pragma unroll
    for (int cb = 0; cb < 4; ++cb) {
        int col  = wcol0 + cb * 16 + l16;
        float bias = b1[col];
        #pragma unroll
        for (int rb = 0; rb < 4; ++rb)
            #pragma unroll
            for (int r = 0; r < 4; ++r) {
                int row = rb * 16 + quad * 4 + r;   // C/D: col=lane&15, row=quad*4+reg
                sh_u[lds_idx(row, col)] =
                    f32_to_bf16_rne(fast_tanh(acc[rb][cb][r] + bias));
            }
    }
    __syncthreads();

    // ================= GEMM2: s = u @ W2^T; accumulate l,g =================
    #pragma unroll
    for (int rb = 0; rb < 4; ++rb)
        #pragma unroll
        for (int cb = 0; cb < 4; ++cb) acc[rb][cb] = (f32x4){0.f, 0.f, 0.f, 0.f};

    {
        const short* Bb = W2b + (size_t)(wcol0 + l16) * DDIM + kq;
        bf16x8 bcur[4], bnxt[4];
        #pragma unroll
        for (int cb = 0; cb < 4; ++cb)
            bcur[cb] = *(const bf16x8*)(Bb + cb * 16 * DDIM);

        for (int k0 = 0; k0 < DDIM; k0 += 32) {
            bf16x8 af[4];
            #pragma unroll
            for (int rb = 0; rb < 4; ++rb)
                af[rb] = *(const bf16x8*)&sh_u[lds_idx(rb * 16 + l16, k0 + kq)];
            #pragma unroll
            for (int cb = 0; cb < 4; ++cb)
                bnxt[cb] = *(const bf16x8*)(Bb + cb * 16 * DDIM + k0 + 32);
            #pragma unroll
            for (int cb = 0; cb < 4; ++cb)
                #pragma unroll
                for (int rb = 0; rb < 4; ++rb)
                    acc[rb][cb] = __builtin_amdgcn_mfma_f32_16x16x32_bf16(
                        af[rb], bcur[cb], acc[rb][cb], 0, 0, 0);
            #pragma unroll
            for (int cb = 0; cb < 4; ++cb) bcur[cb] = bnxt[cb];
        }
    }

    // epilogue 2: e = exp(s); l += e; g += e*h; reduce across quads; atomics
    #pragma unroll
    for (int cb = 0; cb < 4; ++cb) {
        int col = wcol0 + cb * 16 + l16;
        float lsum = 0.f, gsum = 0.f;
        #pragma unroll
        for (int rb = 0; rb < 4; ++rb)
            #pragma unroll
            for (int r = 0; r < 4; ++r) {
                int row = rb * 16 + quad * 4 + r;
                float e  = __expf(acc[rb][cb][r]);   // |s| small: no max-sub needed
                float hv = bf16_to_f32(sh_h[lds_idx(row, col)]);
                lsum += e;
                gsum += e * hv;
            }
        // column sums live in the 4 quads (lanes l16, +16, +32, +48)
        lsum += __shfl_xor(lsum, 16);  lsum += __shfl_xor(lsum, 32);
        gsum += __shfl_xor(gsum, 16);  gsum += __shfl_xor(gsum, 32);
        if (quad == 0) {
            atomicAdd(&lbuf[b * DDIM + col], lsum);
            atomicAdd(&gbuf[b * DDIM + col], gsum);
        }
    }
}

// --- kernel 3: out[d] = sum_b g[b,d] / l[b,d] --------------------------------
__global__ void finish_kernel(const float* __restrict__ lbuf,
                              const float* __restrict__ gbuf,
                              float* __restrict__ out) {
    int d = blockIdx.x * blockDim.x + threadIdx.x;   // 0..511
    float s = 0.f;
    #pragma unroll
    for (int b = 0; b < BATCH; ++b)
        s += gbuf[b * DDIM + d] / lbuf[b * DDIM + d];
    out[d] = s;
}

extern "C" void kernel_launch(void* const* d_in, const int* in_sizes, int n_in,
                              void* d_out, int out_size, void* d_ws, size_t ws_size,
                              hipStream_t stream) {
    const float* h  = (const float*)d_in[0];
    const float* W1 = (const float*)d_in[1];
    const float* b1 = (const float*)d_in[2];
    const float* W2 = (const float*)d_in[3];
    float* out = (float*)d_out;

    char* ws = (char*)d_ws;
    short* W1b = (short*)ws;                              // 512 KB
    short* W2b = (short*)(ws + 512 * 1024);               // 512 KB
    float* lbuf = (float*)(ws + 1024 * 1024);             // 64 KB
    float* gbuf = (float*)(ws + 1024 * 1024 + 64 * 1024); // 64 KB

    prep_kernel<<<(DDIM * DDIM) / 256, 256, 0, stream>>>(W1, W2, W1b, W2b, lbuf, gbuf);
    main_kernel<<<(BATCH * TLEN) / BM, BLOCK, 0, stream>>>(h, W1b, b1, W2b, lbuf, gbuf);
    finish_kernel<<<2, 256, 0, stream>>>(lbuf, gbuf, out);
}